// Round 13
// baseline (161.396 us; speedup 1.0000x reference)
//
#include <hip/hip_runtime.h>
#include <stdint.h>

// Problem constants: bs=16, Q=1024, P=8, D=256, Cin=64, H=W=128, Cout=256.

typedef __attribute__((ext_vector_type(8))) short short8;   // 8 bf16 (4 VGPR)
typedef __attribute__((ext_vector_type(4))) float f32x4;    // MFMA acc

__device__ __forceinline__ unsigned short f2bf(float f) {
  union { float f; unsigned int u; } v; v.f = f;
  unsigned int r = (v.u + 0x7FFFu + ((v.u >> 16) & 1u)) >> 16;  // RNE
  return (unsigned short)r;
}
__device__ __forceinline__ float bf2f(unsigned short h) {
  union { unsigned int u; float f; } v; v.u = ((unsigned int)h) << 16;
  return v.f;
}

// async global->LDS, 16B per lane; LDS dest wave-uniform (HW adds lane*16),
// global src per-lane.
__device__ __forceinline__ void gload_lds16(const void* g, void* l) {
  __builtin_amdgcn_global_load_lds(
      (const __attribute__((address_space(1))) unsigned int*)g,
      (__attribute__((address_space(3))) unsigned int*)l, 16, 0, 0);
}

// ---------------------------------------------------------------------------
// K1: bev (16,64,128,128) f32 NCHW -> bev_nhwc (16,128,128,64) bf16 (unchanged)
// ---------------------------------------------------------------------------
__global__ __launch_bounds__(256) void k1_transpose(const float* __restrict__ bev,
                                                    unsigned short* __restrict__ nhwc) {
  __shared__ __align__(16) float lds[64 * 32 * 4];
  const int b = blockIdx.x >> 7, y = blockIdx.x & 127;
  const int t = threadIdx.x;
  const float* src = bev + (size_t)(b * 64) * 16384 + y * 128;
#pragma unroll
  for (int k = 0; k < 8; ++k) {
    int chunk = k * 256 + t;
    int ic = chunk >> 5, xq = chunk & 31;
    float4 v = *(const float4*)(src + ic * 16384 + xq * 4);
    int slot = xq ^ (ic >> 3);
    *(float4*)&lds[(ic * 32 + slot) * 4] = v;
  }
  __syncthreads();
  unsigned short* dst = nhwc + (size_t)blockIdx.x * 8192;
#pragma unroll
  for (int k = 0; k < 4; ++k) {
    int co = k * 256 + t;
    int x = co >> 3, icg = co & 7;
    int slot = (x >> 2) ^ icg;
    int w = x & 3;
    uint4 u;
    unsigned int* up = (unsigned int*)&u;
#pragma unroll
    for (int jj = 0; jj < 4; ++jj) {
      float v0 = lds[((icg * 8 + 2 * jj) * 32 + slot) * 4 + w];
      float v1 = lds[((icg * 8 + 2 * jj + 1) * 32 + slot) * 4 + w];
      up[jj] = (unsigned int)f2bf(v0) | ((unsigned int)f2bf(v1) << 16);
    }
    *(uint4*)(dst + x * 64 + icg * 8) = u;
  }
}

// ---------------------------------------------------------------------------
// K1b: pack weights (unchanged layouts)
//   wconv[o][gg8][oc256][j8] = conv_w[oc][gg*8+j][o/3][o%3]
//   wout [cg32][d256][j8]    = out_w[d][cg*8+j]
// ---------------------------------------------------------------------------
__global__ __launch_bounds__(256) void k1b_pack(const float* __restrict__ conv_w,
                                                const float* __restrict__ out_w,
                                                unsigned short* __restrict__ wconv,
                                                unsigned short* __restrict__ wout,
                                                float* __restrict__ zp) {
  const int tid = blockIdx.x * 256 + threadIdx.x;
  for (int idx = tid; idx < 9 * 8 * 256 * 8; idx += 16384) {
    int j = idx & 7, oc = (idx >> 3) & 255, g = (idx >> 11) & 7, o = idx >> 14;
    wconv[idx] = f2bf(conv_w[(oc * 64 + g * 8 + j) * 9 + o]);
  }
  for (int idx = tid; idx < 32 * 256 * 8; idx += 16384) {
    int j = idx & 7, d = (idx >> 3) & 255, g = idx >> 11;
    wout[idx] = f2bf(out_w[d * 256 + g * 8 + j]);
  }
  if (tid < 64) zp[tid] = 0.0f;
}

// ---------------------------------------------------------------------------
// K2 v12: occupancy-first variant — 3 waves/SIMD (m114 overlap regime).
// 4096 blocks x 256 thr; block = (b, y, oc-half): 128 pix x 128 oc.
// 4 waves = 2 oc x 2 pix quarters; wave tile 64oc x 64pix, acc[4][4]=64 AGPR;
// A dbuf 32 + B 16 + addr => ~150 regs/wave, capped by __launch_bounds__(256,3).
// LDS 50KB x 3 blocks/CU = 150KB -> 12 waves/CU = 3/SIMD. Barrier-free loop,
// setprio, A global dbuf dist-2, read-only 3-row halo (staged 2x per row: the
// two oc-halves; adjacent in grid for L2 sharing). Same store pattern as v10.
// ---------------------------------------------------------------------------
#define K2_LOADA(s, A) do {                                                   \
    _Pragma("unroll")                                                         \
    for (int ocf_ = 0; ocf_ < 4; ++ocf_)                                      \
      A[ocf_] = gA[(4 * (s) + g) * 256 + ocb0 + ocf_ * 16 + l15];             \
  } while (0)

#define K2_READB(s, B) do {                                                   \
    const int o_ = (s) >> 1, ich_ = (s) & 1;                                  \
    const int dyr_ = o_ / 3, dx_ = o_ - dyr_ * 3 - 1;                         \
    _Pragma("unroll")                                                         \
    for (int pf_ = 0; pf_ < 4; ++pf_)                                         \
      B[pf_] = lin[(dyr_ * 8 + ich_ * 4 + g) * 130 + 1 + dx_ + xb +           \
                   pf_ * 16 + l15];                                           \
  } while (0)

#define K2_MF(A, B) do {                                                      \
    _Pragma("unroll")                                                         \
    for (int ocf_ = 0; ocf_ < 4; ++ocf_)                                      \
      _Pragma("unroll")                                                       \
      for (int pf_ = 0; pf_ < 4; ++pf_)                                       \
        acc[ocf_][pf_] = __builtin_amdgcn_mfma_f32_16x16x32_bf16(             \
            A[ocf_], B[pf_], acc[ocf_][pf_], 0, 0, 0);                        \
  } while (0)

__global__ __launch_bounds__(256, 3) void k2_conv(const unsigned short* __restrict__ nhwc,
                                                  const unsigned short* __restrict__ wconv,
                                                  const float* __restrict__ conv_b,
                                                  const float* __restrict__ zp,
                                                  unsigned short* __restrict__ value) {
  __shared__ __align__(16) char smem[50176];     // 3-row halo 49,920B + pad
  const short8* lin = (const short8*)smem;
  const short8* gA = (const short8*)wconv;
  const int bid = blockIdx.x;
  const int swz = (bid & 7) * 512 + (bid >> 3);    // bijective XCD swizzle
  const int b = swz >> 8, y = (swz >> 1) & 127, och = swz & 1;
  const int t = threadIdx.x, wid = t >> 6, lane = t & 63;
  const int wo = wid >> 1;                         // oc-64-half within block
  const int xb = (wid & 1) * 64;                   // pixel-half base
  const int g = lane >> 4, l15 = lane & 15;
  const int ocb0 = och * 128 + wo * 64;            // wave's oc base (0..255)

  // ---- prologue: stage input rows y-1..y+1 (3120 chunks = 49 issues) ----
  const unsigned short* bevb = nhwc + (size_t)b * (128 * 128 * 64);
  for (int i = wid; i < 49; i += 4) {
    const int chunk = i * 64 + lane;
    const void* src = (const void*)zp;
    if (chunk < 3120) {
      const int ridx = chunk / 1040;
      const int rem = chunk - ridx * 1040;
      const int icg = rem / 130;
      const int c = rem - icg * 130;
      const int yy = y - 1 + ridx, xx = c - 1;
      if (yy >= 0 && yy < 128 && xx >= 0 && xx < 128)
        src = (const void*)(bevb + ((yy * 128 + xx) * 64 + icg * 8));
    }
    gload_lds16(src, smem + i * 1024);             // issue 48 tail pads into smem[49152..]
  }
  __syncthreads();   // drains gload_lds (vmcnt0) + barrier; LDS read-only after

  const f32x4 z4 = {0.f, 0.f, 0.f, 0.f};
  f32x4 acc[4][4];
#pragma unroll
  for (int i = 0; i < 4; ++i)
#pragma unroll
    for (int j = 0; j < 4; ++j) acc[i][j] = z4;

  short8 A0[4], A1[4], B[4];
  K2_LOADA(0, A0);
  K2_LOADA(1, A1);

#pragma unroll
  for (int s = 0; s < 18; ++s) {
    K2_READB(s, B);                                 // 4 LDS reads this step
    __builtin_amdgcn_s_setprio(1);
    if (s & 1) {
      K2_MF(A1, B);
      __builtin_amdgcn_s_setprio(0);
      if (s + 2 < 18) K2_LOADA(s + 2, A1);          // global prefetch dist-2
    } else {
      K2_MF(A0, B);
      __builtin_amdgcn_s_setprio(0);
      if (s + 2 < 18) K2_LOADA(s + 2, A0);
    }
  }

  // ---- epilogue: bias + relu; pf-outer store order for write coalescing ----
  unsigned short* vrow = value + (((size_t)(b * 128 + y) * 128 + xb + l15) * 256);
  float4 cb4[4];
#pragma unroll
  for (int ocf = 0; ocf < 4; ++ocf)
    cb4[ocf] = *(const float4*)(conv_b + ocb0 + ocf * 16 + g * 4);
#pragma unroll
  for (int pf = 0; pf < 4; ++pf) {
#pragma unroll
    for (int ocf = 0; ocf < 4; ++ocf) {
      const int ocb = ocb0 + ocf * 16 + g * 4;
      ushort4 ov;
      float v0 = acc[ocf][pf][0] + cb4[ocf].x; ov.x = f2bf(v0 > 0.f ? v0 : 0.f);
      float v1 = acc[ocf][pf][1] + cb4[ocf].y; ov.y = f2bf(v1 > 0.f ? v1 : 0.f);
      float v2 = acc[ocf][pf][2] + cb4[ocf].z; ov.z = f2bf(v2 > 0.f ? v2 : 0.f);
      float v3 = acc[ocf][pf][3] + cb4[ocf].w; ov.w = f2bf(v3 > 0.f ? v3 : 0.f);
      *(ushort4*)(vrow + (size_t)pf * 16 * 256 + ocb) = ov;
    }
  }
}

// ---------------------------------------------------------------------------
// K3 v3 (unchanged): 2 queries/wave, lane owns 8 channels (b128 corner loads).
// ---------------------------------------------------------------------------
__global__ __launch_bounds__(256) void k3_sample(const float* __restrict__ queries,
                                                 const float* __restrict__ traj,
                                                 const float* __restrict__ attn_w,
                                                 const float* __restrict__ attn_b,
                                                 const unsigned short* __restrict__ value,
                                                 unsigned short* __restrict__ S) {
  const int wid = threadIdx.x >> 6, lane = threadIdx.x & 63;
  const int half = lane >> 5, hl = lane & 31;
  const int bid = blockIdx.x;
  const int sbid = (bid & 7) * 256 + (bid >> 3);   // bijective XCD swizzle
  const int qg = sbid * 8 + wid * 2 + half;        // 0..16383
  const int b = qg >> 10;

  const float4 q0 = *(const float4*)(queries + (size_t)qg * 256 + hl * 8);
  const float4 q1 = *(const float4*)(queries + (size_t)qg * 256 + hl * 8 + 4);
  float a[8];
#pragma unroll
  for (int p = 0; p < 8; ++p) {
    const float4 w0 = *(const float4*)(attn_w + p * 256 + hl * 8);
    const float4 w1 = *(const float4*)(attn_w + p * 256 + hl * 8 + 4);
    float d = q0.x * w0.x + q0.y * w0.y + q0.z * w0.z + q0.w * w0.w
            + q1.x * w1.x + q1.y * w1.y + q1.z * w1.z + q1.w * w1.w;
#pragma unroll
    for (int off = 16; off >= 1; off >>= 1) d += __shfl_xor(d, off);
    a[p] = d + attn_b[p];
  }
  float mx = a[0];
#pragma unroll
  for (int p = 1; p < 8; ++p) mx = fmaxf(mx, a[p]);
  float ssum = 0.f;
#pragma unroll
  for (int p = 0; p < 8; ++p) { a[p] = __expf(a[p] - mx); ssum += a[p]; }
  const float inv = 1.f / ssum;

  float acc[8] = {0.f, 0.f, 0.f, 0.f, 0.f, 0.f, 0.f, 0.f};
  const unsigned short* vb = value + (size_t)b * (128 * 128 * 256);
#pragma unroll
  for (int p = 0; p < 8; ++p) {
    const float ty = traj[(qg * 8 + p) * 2 + 0];
    const float tx = traj[(qg * 8 + p) * 2 + 1];
    const float fx = (tx * 0.03125f + 1.f) * 64.f - 0.5f;   // grid x from traj[...,1]
    const float fy = (ty * 0.03125f + 1.f) * 64.f - 0.5f;   // grid y from traj[...,0]
    const float fx0 = floorf(fx), fy0 = floorf(fy);
    const int ix0 = (int)fx0, iy0 = (int)fy0;
    const float wx1 = fx - fx0, wx0 = 1.f - wx1;
    const float wy1 = fy - fy0, wy0 = 1.f - wy1;
    const float ap = a[p] * inv;
    const float cw[4] = {wx0 * wy0 * ap, wx1 * wy0 * ap, wx0 * wy1 * ap, wx1 * wy1 * ap};
#pragma unroll
    for (int cc = 0; cc < 4; ++cc) {
      const int cx = ix0 + (cc & 1), cy = iy0 + (cc >> 1);
      const bool valid = (cx >= 0) & (cx < 128) & (cy >= 0) & (cy < 128);
      const float w = valid ? cw[cc] : 0.f;
      const int cxc = min(max(cx, 0), 127), cyc = min(max(cy, 0), 127);
      const short8 v = *(const short8*)(vb + (cyc * 128 + cxc) * 256 + hl * 8);
#pragma unroll
      for (int j = 0; j < 8; ++j) acc[j] += w * bf2f((unsigned short)v[j]);
    }
  }
  short8 o;
#pragma unroll
  for (int j = 0; j < 8; ++j) o[j] = (short)f2bf(acc[j]);
  *(short8*)(S + (size_t)qg * 256 + hl * 8) = o;
}

// ---------------------------------------------------------------------------
// K4 v4 (unchanged): barrier-free, S read directly from L2-resident global.
// ---------------------------------------------------------------------------
__global__ __launch_bounds__(256) void k4_proj(const unsigned short* __restrict__ S,
                                               const unsigned short* __restrict__ wout,
                                               const float* __restrict__ out_b,
                                               const float* __restrict__ queries,
                                               float* __restrict__ out) {
  const short8* wp8 = (const short8*)wout;
  const short8* Sp = (const short8*)S;           // [q][32 chunks of 8c]
  const int t = threadIdx.x, wid = t >> 6, lane = t & 63;
  const int q0 = blockIdx.x * 64;
  const int g = lane >> 4, l15 = lane & 15;
  const f32x4 z4 = {0.f, 0.f, 0.f, 0.f};
  f32x4 acc[4][4];
#pragma unroll
  for (int i = 0; i < 4; ++i)
#pragma unroll
    for (int j = 0; j < 4; ++j) acc[i][j] = z4;

#pragma unroll
  for (int ks = 0; ks < 8; ++ks) {
    short8 af[4];
#pragma unroll
    for (int df = 0; df < 4; ++df)
      af[df] = wp8[(ks * 4 + g) * 256 + wid * 64 + df * 16 + l15];
    short8 bf[4];
#pragma unroll
    for (int qf = 0; qf < 4; ++qf)
      bf[qf] = Sp[(size_t)(q0 + qf * 16 + l15) * 32 + ks * 4 + g];
#pragma unroll
    for (int df = 0; df < 4; ++df)
#pragma unroll
      for (int qf = 0; qf < 4; ++qf)
        acc[df][qf] = __builtin_amdgcn_mfma_f32_16x16x32_bf16(af[df], bf[qf], acc[df][qf], 0, 0, 0);
  }

#pragma unroll
  for (int df = 0; df < 4; ++df) {
    const int db = wid * 64 + df * 16 + g * 4;
    const float4 ob4 = *(const float4*)(out_b + db);
#pragma unroll
    for (int qf = 0; qf < 4; ++qf) {
      const int q = q0 + qf * 16 + l15;
      const float4 qv = *(const float4*)(queries + (size_t)q * 256 + db);
      float4 ov;
      ov.x = acc[df][qf][0] + ob4.x + qv.x;
      ov.y = acc[df][qf][1] + ob4.y + qv.y;
      ov.z = acc[df][qf][2] + ob4.z + qv.z;
      ov.w = acc[df][qf][3] + ob4.w + qv.w;
      *(float4*)(out + (size_t)q * 256 + db) = ov;
    }
  }
}

// ---------------------------------------------------------------------------
extern "C" void kernel_launch(void* const* d_in, const int* in_sizes, int n_in,
                              void* d_out, int out_size, void* d_ws, size_t ws_size,
                              hipStream_t stream) {
  const float* queries = (const float*)d_in[0];
  const float* traj    = (const float*)d_in[1];
  const float* bev     = (const float*)d_in[2];
  const float* attn_w  = (const float*)d_in[4];
  const float* attn_b  = (const float*)d_in[5];
  const float* conv_w  = (const float*)d_in[6];
  const float* conv_b  = (const float*)d_in[7];
  const float* out_w   = (const float*)d_in[8];
  const float* out_b   = (const float*)d_in[9];
  float* out = (float*)d_out;

  char* ws = (char*)d_ws;
  unsigned short* bev_nhwc = (unsigned short*)(ws);               //  33,554,432 B
  unsigned short* value    = (unsigned short*)(ws + 33554432);    // 134,217,728 B
  unsigned short* wconv    = (unsigned short*)(ws + 167772160);   //     294,912 B
  unsigned short* wout     = (unsigned short*)(ws + 168067072);   //     131,072 B
  unsigned short* Sbuf     = (unsigned short*)(ws + 168198144);   //   8,388,608 B
  float*          zp       = (float*)(ws + 176586752);            //         256 B

  k1_transpose<<<2048, 256, 0, stream>>>(bev, bev_nhwc);
  k1b_pack<<<64, 256, 0, stream>>>(conv_w, out_w, wconv, wout, zp);
  k2_conv<<<4096, 256, 0, stream>>>(bev_nhwc, wconv, conv_b, zp, value);
  k3_sample<<<2048, 256, 0, stream>>>(queries, traj, attn_w, attn_b, value, Sbuf);
  k4_proj<<<256, 256, 0, stream>>>(Sbuf, wout, out_b, queries, out);
}

// Round 14
// 157.242 us; speedup vs baseline: 1.0264x; 1.0264x over previous
//
#include <hip/hip_runtime.h>
#include <stdint.h>

// Problem constants: bs=16, Q=1024, P=8, D=256, Cin=64, H=W=128, Cout=256.

typedef __attribute__((ext_vector_type(8))) short short8;    // 8 bf16 (4 VGPR)
typedef __attribute__((ext_vector_type(4))) float f32x4;     // 16x16 MFMA acc
typedef __attribute__((ext_vector_type(16))) float f32x16;   // 32x32 MFMA acc

__device__ __forceinline__ unsigned short f2bf(float f) {
  union { float f; unsigned int u; } v; v.f = f;
  unsigned int r = (v.u + 0x7FFFu + ((v.u >> 16) & 1u)) >> 16;  // RNE
  return (unsigned short)r;
}
__device__ __forceinline__ float bf2f(unsigned short h) {
  union { unsigned int u; float f; } v; v.u = ((unsigned int)h) << 16;
  return v.f;
}

// async global->LDS, 16B per lane; LDS dest wave-uniform (HW adds lane*16),
// global src per-lane.
__device__ __forceinline__ void gload_lds16(const void* g, void* l) {
  __builtin_amdgcn_global_load_lds(
      (const __attribute__((address_space(1))) unsigned int*)g,
      (__attribute__((address_space(3))) unsigned int*)l, 16, 0, 0);
}

// ---------------------------------------------------------------------------
// K1: bev (16,64,128,128) f32 NCHW -> bev_nhwc (16,128,128,64) bf16 (unchanged)
// ---------------------------------------------------------------------------
__global__ __launch_bounds__(256) void k1_transpose(const float* __restrict__ bev,
                                                    unsigned short* __restrict__ nhwc) {
  __shared__ __align__(16) float lds[64 * 32 * 4];
  const int b = blockIdx.x >> 7, y = blockIdx.x & 127;
  const int t = threadIdx.x;
  const float* src = bev + (size_t)(b * 64) * 16384 + y * 128;
#pragma unroll
  for (int k = 0; k < 8; ++k) {
    int chunk = k * 256 + t;
    int ic = chunk >> 5, xq = chunk & 31;
    float4 v = *(const float4*)(src + ic * 16384 + xq * 4);
    int slot = xq ^ (ic >> 3);
    *(float4*)&lds[(ic * 32 + slot) * 4] = v;
  }
  __syncthreads();
  unsigned short* dst = nhwc + (size_t)blockIdx.x * 8192;
#pragma unroll
  for (int k = 0; k < 4; ++k) {
    int co = k * 256 + t;
    int x = co >> 3, icg = co & 7;
    int slot = (x >> 2) ^ icg;
    int w = x & 3;
    uint4 u;
    unsigned int* up = (unsigned int*)&u;
#pragma unroll
    for (int jj = 0; jj < 4; ++jj) {
      float v0 = lds[((icg * 8 + 2 * jj) * 32 + slot) * 4 + w];
      float v1 = lds[((icg * 8 + 2 * jj + 1) * 32 + slot) * 4 + w];
      up[jj] = (unsigned int)f2bf(v0) | ((unsigned int)f2bf(v1) << 16);
    }
    *(uint4*)(dst + x * 64 + icg * 8) = u;
  }
}

// ---------------------------------------------------------------------------
// K1b: pack weights (unchanged layouts)
//   wconv[o][gg8][oc256][j8] = conv_w[oc][gg*8+j][o/3][o%3]
//   wout [cg32][d256][j8]    = out_w[d][cg*8+j]
// ---------------------------------------------------------------------------
__global__ __launch_bounds__(256) void k1b_pack(const float* __restrict__ conv_w,
                                                const float* __restrict__ out_w,
                                                unsigned short* __restrict__ wconv,
                                                unsigned short* __restrict__ wout,
                                                float* __restrict__ zp) {
  const int tid = blockIdx.x * 256 + threadIdx.x;
  for (int idx = tid; idx < 9 * 8 * 256 * 8; idx += 16384) {
    int j = idx & 7, oc = (idx >> 3) & 255, g = (idx >> 11) & 7, o = idx >> 14;
    wconv[idx] = f2bf(conv_w[(oc * 64 + g * 8 + j) * 9 + o]);
  }
  for (int idx = tid; idx < 32 * 256 * 8; idx += 16384) {
    int j = idx & 7, d = (idx >> 3) & 255, g = idx >> 11;
    wout[idx] = f2bf(out_w[d * 256 + g * 8 + j]);
  }
  if (tid < 64) zp[tid] = 0.0f;
}

// ---------------------------------------------------------------------------
// K2 v13 = v10 geometry with 32x32x16 MFMA (m119: 2495 vs 2176 TF, and half
// the MFMA instruction count -> issue-slot relief in a latency-bound loop).
// 2048 blocks x 256 thr; block = (b,y): 128 pix x 256 oc. 4 waves = 4 oc-
// quarters; wave 64oc x 128pix = 2 ocfrag x 4 pixfrag of 32x32, acc 8 x f32x16
// = 128 AGPR. Per K32 step: 4 A global loads (dbuf dist-2), 8 B ds_read_b128,
// 16 MFMA. Fragment maps: A/B lane = (l&31 -> row/col, l>>5 -> k-half of 8);
// C/D: col(pix)=l&31, row(oc)=(reg&3)+8*(reg>>2)+4*(l>>5) [m74/m101].
// Barrier-free loop, setprio, read-only 3-row halo, 2 blocks/CU desynced.
// ---------------------------------------------------------------------------
#define K2_LOADA(s, A) do {                                                   \
    _Pragma("unroll")                                                         \
    for (int of_ = 0; of_ < 2; ++of_)                                         \
      _Pragma("unroll")                                                       \
      for (int kk_ = 0; kk_ < 2; ++kk_)                                       \
        A[of_ * 2 + kk_] = gA[(4 * (s) + 2 * kk_ + h5) * 256 + wo * 64 +      \
                              of_ * 32 + l31];                                \
  } while (0)

#define K2_READB(s, B) do {                                                   \
    const int o_ = (s) >> 1, ich_ = (s) & 1;                                  \
    const int dyr_ = o_ / 3, dx_ = o_ - dyr_ * 3 - 1;                         \
    _Pragma("unroll")                                                         \
    for (int pf_ = 0; pf_ < 4; ++pf_)                                         \
      _Pragma("unroll")                                                       \
      for (int kk_ = 0; kk_ < 2; ++kk_)                                       \
        B[pf_ * 2 + kk_] = lin[(dyr_ * 8 + ich_ * 4 + 2 * kk_ + h5) * 130 +   \
                               1 + dx_ + pf_ * 32 + l31];                     \
  } while (0)

#define K2_MF(A, B) do {                                                      \
    _Pragma("unroll")                                                         \
    for (int kk_ = 0; kk_ < 2; ++kk_)                                         \
      _Pragma("unroll")                                                       \
      for (int of_ = 0; of_ < 2; ++of_)                                       \
        _Pragma("unroll")                                                     \
        for (int pf_ = 0; pf_ < 4; ++pf_)                                     \
          acc[of_][pf_] = __builtin_amdgcn_mfma_f32_32x32x16_bf16(            \
              A[of_ * 2 + kk_], B[pf_ * 2 + kk_], acc[of_][pf_], 0, 0, 0);    \
  } while (0)

__global__ __launch_bounds__(256, 2) void k2_conv(const unsigned short* __restrict__ nhwc,
                                                  const unsigned short* __restrict__ wconv,
                                                  const float* __restrict__ conv_b,
                                                  const float* __restrict__ zp,
                                                  unsigned short* __restrict__ value) {
  __shared__ __align__(16) char smem[50176];     // 3-row halo 49,920B + pad
  const short8* lin = (const short8*)smem;
  const short8* gA = (const short8*)wconv;
  const int bid = blockIdx.x;
  const int swz = (bid & 7) * 256 + (bid >> 3);    // XCD swizzle: 2 images/XCD
  const int b = swz >> 7, y = swz & 127;
  const int t = threadIdx.x, wid = t >> 6, lane = t & 63;
  const int wo = wid;                              // oc-quarter
  const int h5 = lane >> 5, l31 = lane & 31;
  const int g = lane >> 4, l15 = lane & 15;        // (prologue indexing only)
  (void)g; (void)l15;

  // ---- prologue: stage input rows y-1..y+1 (3120 chunks = 49 issues) ----
  const unsigned short* bevb = nhwc + (size_t)b * (128 * 128 * 64);
  for (int i = wid; i < 49; i += 4) {
    const int chunk = i * 64 + lane;
    const void* src = (const void*)zp;
    if (chunk < 3120) {
      const int ridx = chunk / 1040;
      const int rem = chunk - ridx * 1040;
      const int icg = rem / 130;
      const int c = rem - icg * 130;
      const int yy = y - 1 + ridx, xx = c - 1;
      if (yy >= 0 && yy < 128 && xx >= 0 && xx < 128)
        src = (const void*)(bevb + ((yy * 128 + xx) * 64 + icg * 8));
    }
    gload_lds16(src, smem + i * 1024);             // issue 48 tail pads into smem[49152..]
  }
  __syncthreads();   // drains gload_lds (vmcnt0) + barrier; LDS read-only after

  f32x16 acc[2][4];
#pragma unroll
  for (int i = 0; i < 2; ++i)
#pragma unroll
    for (int j = 0; j < 4; ++j)
#pragma unroll
      for (int e = 0; e < 16; ++e) acc[i][j][e] = 0.f;

  short8 A0[4], A1[4], B[8];
  K2_LOADA(0, A0);
  K2_LOADA(1, A1);

#pragma unroll
  for (int s = 0; s < 18; ++s) {
    K2_READB(s, B);                                 // 8 LDS reads this step
    __builtin_amdgcn_s_setprio(1);
    if (s & 1) {
      K2_MF(A1, B);
      __builtin_amdgcn_s_setprio(0);
      if (s + 2 < 18) K2_LOADA(s + 2, A1);          // global prefetch dist-2
    } else {
      K2_MF(A0, B);
      __builtin_amdgcn_s_setprio(0);
      if (s + 2 < 18) K2_LOADA(s + 2, A0);
    }
  }

  // ---- epilogue: bias + relu; pf-outer (pixel-line-grouped) ushort4 stores -
  unsigned short* vbase = value + ((size_t)(b * 128 + y) * 128) * 256;
#pragma unroll
  for (int pf = 0; pf < 4; ++pf) {
    const int pix = pf * 32 + l31;
    unsigned short* vp = vbase + (size_t)pix * 256;
#pragma unroll
    for (int of = 0; of < 2; ++of) {
#pragma unroll
      for (int q = 0; q < 4; ++q) {
        const int oc = wo * 64 + of * 32 + 4 * h5 + 8 * q;
        const float4 cb = *(const float4*)(conv_b + oc);
        ushort4 ov;
        float v0 = acc[of][pf][q * 4 + 0] + cb.x; ov.x = f2bf(v0 > 0.f ? v0 : 0.f);
        float v1 = acc[of][pf][q * 4 + 1] + cb.y; ov.y = f2bf(v1 > 0.f ? v1 : 0.f);
        float v2 = acc[of][pf][q * 4 + 2] + cb.z; ov.z = f2bf(v2 > 0.f ? v2 : 0.f);
        float v3 = acc[of][pf][q * 4 + 3] + cb.w; ov.w = f2bf(v3 > 0.f ? v3 : 0.f);
        *(ushort4*)(vp + oc) = ov;
      }
    }
  }
}

// ---------------------------------------------------------------------------
// K3 v3 (unchanged): 2 queries/wave, lane owns 8 channels (b128 corner loads).
// ---------------------------------------------------------------------------
__global__ __launch_bounds__(256) void k3_sample(const float* __restrict__ queries,
                                                 const float* __restrict__ traj,
                                                 const float* __restrict__ attn_w,
                                                 const float* __restrict__ attn_b,
                                                 const unsigned short* __restrict__ value,
                                                 unsigned short* __restrict__ S) {
  const int wid = threadIdx.x >> 6, lane = threadIdx.x & 63;
  const int half = lane >> 5, hl = lane & 31;
  const int bid = blockIdx.x;
  const int sbid = (bid & 7) * 256 + (bid >> 3);   // bijective XCD swizzle
  const int qg = sbid * 8 + wid * 2 + half;        // 0..16383
  const int b = qg >> 10;

  const float4 q0 = *(const float4*)(queries + (size_t)qg * 256 + hl * 8);
  const float4 q1 = *(const float4*)(queries + (size_t)qg * 256 + hl * 8 + 4);
  float a[8];
#pragma unroll
  for (int p = 0; p < 8; ++p) {
    const float4 w0 = *(const float4*)(attn_w + p * 256 + hl * 8);
    const float4 w1 = *(const float4*)(attn_w + p * 256 + hl * 8 + 4);
    float d = q0.x * w0.x + q0.y * w0.y + q0.z * w0.z + q0.w * w0.w
            + q1.x * w1.x + q1.y * w1.y + q1.z * w1.z + q1.w * w1.w;
#pragma unroll
    for (int off = 16; off >= 1; off >>= 1) d += __shfl_xor(d, off);
    a[p] = d + attn_b[p];
  }
  float mx = a[0];
#pragma unroll
  for (int p = 1; p < 8; ++p) mx = fmaxf(mx, a[p]);
  float ssum = 0.f;
#pragma unroll
  for (int p = 0; p < 8; ++p) { a[p] = __expf(a[p] - mx); ssum += a[p]; }
  const float inv = 1.f / ssum;

  float acc[8] = {0.f, 0.f, 0.f, 0.f, 0.f, 0.f, 0.f, 0.f};
  const unsigned short* vb = value + (size_t)b * (128 * 128 * 256);
#pragma unroll
  for (int p = 0; p < 8; ++p) {
    const float ty = traj[(qg * 8 + p) * 2 + 0];
    const float tx = traj[(qg * 8 + p) * 2 + 1];
    const float fx = (tx * 0.03125f + 1.f) * 64.f - 0.5f;   // grid x from traj[...,1]
    const float fy = (ty * 0.03125f + 1.f) * 64.f - 0.5f;   // grid y from traj[...,0]
    const float fx0 = floorf(fx), fy0 = floorf(fy);
    const int ix0 = (int)fx0, iy0 = (int)fy0;
    const float wx1 = fx - fx0, wx0 = 1.f - wx1;
    const float wy1 = fy - fy0, wy0 = 1.f - wy1;
    const float ap = a[p] * inv;
    const float cw[4] = {wx0 * wy0 * ap, wx1 * wy0 * ap, wx0 * wy1 * ap, wx1 * wy1 * ap};
#pragma unroll
    for (int cc = 0; cc < 4; ++cc) {
      const int cx = ix0 + (cc & 1), cy = iy0 + (cc >> 1);
      const bool valid = (cx >= 0) & (cx < 128) & (cy >= 0) & (cy < 128);
      const float w = valid ? cw[cc] : 0.f;
      const int cxc = min(max(cx, 0), 127), cyc = min(max(cy, 0), 127);
      const short8 v = *(const short8*)(vb + (cyc * 128 + cxc) * 256 + hl * 8);
#pragma unroll
      for (int j = 0; j < 8; ++j) acc[j] += w * bf2f((unsigned short)v[j]);
    }
  }
  short8 o;
#pragma unroll
  for (int j = 0; j < 8; ++j) o[j] = (short)f2bf(acc[j]);
  *(short8*)(S + (size_t)qg * 256 + hl * 8) = o;
}

// ---------------------------------------------------------------------------
// K4 v4 (unchanged): barrier-free, S read directly from L2-resident global.
// ---------------------------------------------------------------------------
__global__ __launch_bounds__(256) void k4_proj(const unsigned short* __restrict__ S,
                                               const unsigned short* __restrict__ wout,
                                               const float* __restrict__ out_b,
                                               const float* __restrict__ queries,
                                               float* __restrict__ out) {
  const short8* wp8 = (const short8*)wout;
  const short8* Sp = (const short8*)S;           // [q][32 chunks of 8c]
  const int t = threadIdx.x, wid = t >> 6, lane = t & 63;
  const int q0 = blockIdx.x * 64;
  const int g = lane >> 4, l15 = lane & 15;
  const f32x4 z4 = {0.f, 0.f, 0.f, 0.f};
  f32x4 acc[4][4];
#pragma unroll
  for (int i = 0; i < 4; ++i)
#pragma unroll
    for (int j = 0; j < 4; ++j) acc[i][j] = z4;

#pragma unroll
  for (int ks = 0; ks < 8; ++ks) {
    short8 af[4];
#pragma unroll
    for (int df = 0; df < 4; ++df)
      af[df] = wp8[(ks * 4 + g) * 256 + wid * 64 + df * 16 + l15];
    short8 bf[4];
#pragma unroll
    for (int qf = 0; qf < 4; ++qf)
      bf[qf] = Sp[(size_t)(q0 + qf * 16 + l15) * 32 + ks * 4 + g];
#pragma unroll
    for (int df = 0; df < 4; ++df)
#pragma unroll
      for (int qf = 0; qf < 4; ++qf)
        acc[df][qf] = __builtin_amdgcn_mfma_f32_16x16x32_bf16(af[df], bf[qf], acc[df][qf], 0, 0, 0);
  }

#pragma unroll
  for (int df = 0; df < 4; ++df) {
    const int db = wid * 64 + df * 16 + g * 4;
    const float4 ob4 = *(const float4*)(out_b + db);
#pragma unroll
    for (int qf = 0; qf < 4; ++qf) {
      const int q = q0 + qf * 16 + l15;
      const float4 qv = *(const float4*)(queries + (size_t)q * 256 + db);
      float4 ov;
      ov.x = acc[df][qf][0] + ob4.x + qv.x;
      ov.y = acc[df][qf][1] + ob4.y + qv.y;
      ov.z = acc[df][qf][2] + ob4.z + qv.z;
      ov.w = acc[df][qf][3] + ob4.w + qv.w;
      *(float4*)(out + (size_t)q * 256 + db) = ov;
    }
  }
}

// ---------------------------------------------------------------------------
extern "C" void kernel_launch(void* const* d_in, const int* in_sizes, int n_in,
                              void* d_out, int out_size, void* d_ws, size_t ws_size,
                              hipStream_t stream) {
  const float* queries = (const float*)d_in[0];
  const float* traj    = (const float*)d_in[1];
  const float* bev     = (const float*)d_in[2];
  const float* attn_w  = (const float*)d_in[4];
  const float* attn_b  = (const float*)d_in[5];
  const float* conv_w  = (const float*)d_in[6];
  const float* conv_b  = (const float*)d_in[7];
  const float* out_w   = (const float*)d_in[8];
  const float* out_b   = (const float*)d_in[9];
  float* out = (float*)d_out;

  char* ws = (char*)d_ws;
  unsigned short* bev_nhwc = (unsigned short*)(ws);               //  33,554,432 B
  unsigned short* value    = (unsigned short*)(ws + 33554432);    // 134,217,728 B
  unsigned short* wconv    = (unsigned short*)(ws + 167772160);   //     294,912 B
  unsigned short* wout     = (unsigned short*)(ws + 168067072);   //     131,072 B
  unsigned short* Sbuf     = (unsigned short*)(ws + 168198144);   //   8,388,608 B
  float*          zp       = (float*)(ws + 176586752);            //         256 B

  k1_transpose<<<2048, 256, 0, stream>>>(bev, bev_nhwc);
  k1b_pack<<<64, 256, 0, stream>>>(conv_w, out_w, wconv, wout, zp);
  k2_conv<<<2048, 256, 0, stream>>>(bev_nhwc, wconv, conv_b, zp, value);
  k3_sample<<<2048, 256, 0, stream>>>(queries, traj, attn_w, attn_b, value, Sbuf);
  k4_proj<<<256, 256, 0, stream>>>(Sbuf, wout, out_b, queries, out);
}

// Round 15
// 142.674 us; speedup vs baseline: 1.1312x; 1.1021x over previous
//
#include <hip/hip_runtime.h>
#include <stdint.h>

// Problem constants: bs=16, Q=1024, P=8, D=256, Cin=64, H=W=128, Cout=256.

typedef __attribute__((ext_vector_type(8))) short short8;   // 8 bf16 (4 VGPR)
typedef __attribute__((ext_vector_type(4))) float f32x4;    // MFMA acc

__device__ __forceinline__ unsigned short f2bf(float f) {
  union { float f; unsigned int u; } v; v.f = f;
  unsigned int r = (v.u + 0x7FFFu + ((v.u >> 16) & 1u)) >> 16;  // RNE
  return (unsigned short)r;
}
__device__ __forceinline__ float bf2f(unsigned short h) {
  union { unsigned int u; float f; } v; v.u = ((unsigned int)h) << 16;
  return v.f;
}

// async global->LDS, 16B per lane; LDS dest wave-uniform (HW adds lane*16),
// global src per-lane.
__device__ __forceinline__ void gload_lds16(const void* g, void* l) {
  __builtin_amdgcn_global_load_lds(
      (const __attribute__((address_space(1))) unsigned int*)g,
      (__attribute__((address_space(3))) unsigned int*)l, 16, 0, 0);
}

// ---------------------------------------------------------------------------
// K1 v2: bev (16,64,128,128) f32 NCHW -> bev_nhwc (16,128,128,64) bf16.
// Block = (b, y-PAIR): per-ic reads are 1KB contiguous (one wave = one 1KB
// segment) instead of v1's 512B fragments -> better HBM efficiency.
// LDS 64KB: [yl][ic][slot xor-swizzled][4]; same verified swizzle per row.
// k1b's weight-pack work is folded into the first 64 blocks (saves a launch).
// ---------------------------------------------------------------------------
__global__ __launch_bounds__(256) void k1_transpose(const float* __restrict__ bev,
                                                    unsigned short* __restrict__ nhwc,
                                                    const float* __restrict__ conv_w,
                                                    const float* __restrict__ out_w,
                                                    unsigned short* __restrict__ wconv,
                                                    unsigned short* __restrict__ wout,
                                                    float* __restrict__ zp) {
  __shared__ __align__(16) float lds[2 * 64 * 32 * 4];   // 64 KB
  const int b = blockIdx.x >> 6, yp = blockIdx.x & 63;
  const int y0 = yp * 2;
  const int t = threadIdx.x;
  const float* src = bev + (size_t)(b * 64) * 16384 + y0 * 128;
#pragma unroll
  for (int k = 0; k < 16; ++k) {
    int chunk = k * 256 + t;            // ic(64) x yl(2) x xq(32)
    int ic = chunk >> 6, rem = chunk & 63;
    int yl = rem >> 5, xq = rem & 31;
    float4 v = *(const float4*)(src + ic * 16384 + yl * 128 + xq * 4);
    int slot = xq ^ (ic >> 3);
    *(float4*)&lds[((yl * 64 + ic) * 32 + slot) * 4] = v;
  }
  __syncthreads();
  unsigned short* dst = nhwc + (size_t)(b * 128 + y0) * 8192;
#pragma unroll
  for (int k = 0; k < 8; ++k) {
    int co = k * 256 + t;               // yl(2) x x(128) x icg(8)
    int yl = co >> 10, rem = co & 1023;
    int x = rem >> 3, icg = rem & 7;
    int slot = (x >> 2) ^ icg;
    int w = x & 3;
    uint4 u;
    unsigned int* up = (unsigned int*)&u;
#pragma unroll
    for (int jj = 0; jj < 4; ++jj) {
      float v0 = lds[((yl * 64 + icg * 8 + 2 * jj) * 32 + slot) * 4 + w];
      float v1 = lds[((yl * 64 + icg * 8 + 2 * jj + 1) * 32 + slot) * 4 + w];
      up[jj] = (unsigned int)f2bf(v0) | ((unsigned int)f2bf(v1) << 16);
    }
    *(uint4*)(dst + yl * 8192 + x * 64 + icg * 8) = u;
  }
  // ---- folded k1b: weight pack (first 64 blocks only; tiny) ----
  if (blockIdx.x < 64) {
    const int tid = blockIdx.x * 256 + t;          // 0..16383
    for (int idx = tid; idx < 9 * 8 * 256 * 8; idx += 16384) {
      int j = idx & 7, oc = (idx >> 3) & 255, g = (idx >> 11) & 7, o = idx >> 14;
      wconv[idx] = f2bf(conv_w[(oc * 64 + g * 8 + j) * 9 + o]);
    }
    for (int idx = tid; idx < 32 * 256 * 8; idx += 16384) {
      int j = idx & 7, d = (idx >> 3) & 255, g = idx >> 11;
      wout[idx] = f2bf(out_w[d * 256 + g * 8 + j]);
    }
    if (tid < 64) zp[tid] = 0.0f;
  }
}

// ---------------------------------------------------------------------------
// K2 v11 (reverted to round-12 exact, best measured 87.36us):
// barrier-free 1-row blocks + setprio + in-place pipelined B-refill.
// 2048 blocks x 256 thr; block = (b,y), 128pix x 256oc. 4 waves = 4 distinct
// oc-quarters, wave 64oc x 128pix, acc[4][8]. A: 4 global loads/wave/step,
// dbuf dist-2. B: 8 ds_read_b128/wave/step from read-only 3-row halo.
// 2 blocks/CU desynced.
// ---------------------------------------------------------------------------
#define K2_LOADA(s, A) do {                                                   \
    _Pragma("unroll")                                                         \
    for (int ocf_ = 0; ocf_ < 4; ++ocf_)                                      \
      A[ocf_] = gA[(4 * (s) + g) * 256 + wo * 64 + ocf_ * 16 + l15];          \
  } while (0)

#define K2_READB(s, h, B) do {                                                \
    const int o_ = (s) >> 1, ich_ = (s) & 1;                                  \
    const int dyr_ = o_ / 3, dx_ = o_ - dyr_ * 3 - 1;                         \
    _Pragma("unroll")                                                         \
    for (int pf_ = 0; pf_ < 4; ++pf_)                                         \
      B[pf_] = lin[(dyr_ * 8 + ich_ * 4 + g) * 130 + 1 + dx_ +                \
                   ((h) * 4 + pf_) * 16 + l15];                               \
  } while (0)

#define K2_MF(A, B, h) do {                                                   \
    _Pragma("unroll")                                                         \
    for (int ocf_ = 0; ocf_ < 4; ++ocf_)                                      \
      _Pragma("unroll")                                                       \
      for (int pf_ = 0; pf_ < 4; ++pf_)                                       \
        acc[ocf_][(h) * 4 + pf_] = __builtin_amdgcn_mfma_f32_16x16x32_bf16(   \
            A[ocf_], B[pf_], acc[ocf_][(h) * 4 + pf_], 0, 0, 0);              \
  } while (0)

__global__ __launch_bounds__(256, 2) void k2_conv(const unsigned short* __restrict__ nhwc,
                                                  const unsigned short* __restrict__ wconv,
                                                  const float* __restrict__ conv_b,
                                                  const float* __restrict__ zp,
                                                  unsigned short* __restrict__ value) {
  __shared__ __align__(16) char smem[50176];     // 3-row halo 49,920B + pad
  const short8* lin = (const short8*)smem;
  const short8* gA = (const short8*)wconv;
  const int bid = blockIdx.x;
  const int swz = (bid & 7) * 256 + (bid >> 3);    // XCD swizzle: 2 images/XCD
  const int b = swz >> 7, y = swz & 127;
  const int t = threadIdx.x, wid = t >> 6, lane = t & 63;
  const int wo = wid;                              // oc-quarter
  const int g = lane >> 4, l15 = lane & 15;

  // ---- prologue: stage input rows y-1..y+1 (3120 chunks = 49 issues) ----
  const unsigned short* bevb = nhwc + (size_t)b * (128 * 128 * 64);
  for (int i = wid; i < 49; i += 4) {
    const int chunk = i * 64 + lane;
    const void* src = (const void*)zp;
    if (chunk < 3120) {
      const int ridx = chunk / 1040;
      const int rem = chunk - ridx * 1040;
      const int icg = rem / 130;
      const int c = rem - icg * 130;
      const int yy = y - 1 + ridx, xx = c - 1;
      if (yy >= 0 && yy < 128 && xx >= 0 && xx < 128)
        src = (const void*)(bevb + ((yy * 128 + xx) * 64 + icg * 8));
    }
    gload_lds16(src, smem + i * 1024);             // issue 48 tail pads into smem[49152..]
  }
  __syncthreads();   // drains gload_lds (vmcnt0) + barrier; LDS read-only after

  const f32x4 z4 = {0.f, 0.f, 0.f, 0.f};
  f32x4 acc[4][8];
#pragma unroll
  for (int i = 0; i < 4; ++i)
#pragma unroll
    for (int j = 0; j < 8; ++j) acc[i][j] = z4;

  short8 A0[4], A1[4], B0[4], B1[4];
  K2_LOADA(0, A0);
  K2_LOADA(1, A1);
  K2_READB(0, 0, B0);
  K2_READB(0, 1, B1);

#pragma unroll
  for (int s = 0; s < 18; ++s) {
    __builtin_amdgcn_s_setprio(1);
    if (s & 1) {
      K2_MF(A1, B0, 0);
      if (s < 17) K2_READB(s + 1, 0, B0);          // refill under B1 burst
      K2_MF(A1, B1, 1);
      __builtin_amdgcn_s_setprio(0);
      if (s < 17) K2_READB(s + 1, 1, B1);
      if (s + 2 < 18) K2_LOADA(s + 2, A1);         // global prefetch dist-2
    } else {
      K2_MF(A0, B0, 0);
      if (s < 17) K2_READB(s + 1, 0, B0);
      K2_MF(A0, B1, 1);
      __builtin_amdgcn_s_setprio(0);
      if (s < 17) K2_READB(s + 1, 1, B1);
      if (s + 2 < 18) K2_LOADA(s + 2, A0);
    }
  }

  // ---- epilogue: bias + relu; pf-outer store order for write coalescing ----
  unsigned short* vrow = value + (((size_t)(b * 128 + y) * 128 + l15) * 256);
  float4 cb4[4];
#pragma unroll
  for (int ocf = 0; ocf < 4; ++ocf)
    cb4[ocf] = *(const float4*)(conv_b + wo * 64 + ocf * 16 + g * 4);
#pragma unroll
  for (int pf = 0; pf < 8; ++pf) {
#pragma unroll
    for (int ocf = 0; ocf < 4; ++ocf) {
      const int ocb = wo * 64 + ocf * 16 + g * 4;
      ushort4 ov;
      float v0 = acc[ocf][pf][0] + cb4[ocf].x; ov.x = f2bf(v0 > 0.f ? v0 : 0.f);
      float v1 = acc[ocf][pf][1] + cb4[ocf].y; ov.y = f2bf(v1 > 0.f ? v1 : 0.f);
      float v2 = acc[ocf][pf][2] + cb4[ocf].z; ov.z = f2bf(v2 > 0.f ? v2 : 0.f);
      float v3 = acc[ocf][pf][3] + cb4[ocf].w; ov.w = f2bf(v3 > 0.f ? v3 : 0.f);
      *(ushort4*)(vrow + (size_t)pf * 16 * 256 + ocb) = ov;
    }
  }
}

// ---------------------------------------------------------------------------
// K3 v3 (unchanged): 2 queries/wave, lane owns 8 channels (b128 corner loads).
// ---------------------------------------------------------------------------
__global__ __launch_bounds__(256) void k3_sample(const float* __restrict__ queries,
                                                 const float* __restrict__ traj,
                                                 const float* __restrict__ attn_w,
                                                 const float* __restrict__ attn_b,
                                                 const unsigned short* __restrict__ value,
                                                 unsigned short* __restrict__ S) {
  const int wid = threadIdx.x >> 6, lane = threadIdx.x & 63;
  const int half = lane >> 5, hl = lane & 31;
  const int bid = blockIdx.x;
  const int sbid = (bid & 7) * 256 + (bid >> 3);   // bijective XCD swizzle
  const int qg = sbid * 8 + wid * 2 + half;        // 0..16383
  const int b = qg >> 10;

  const float4 q0 = *(const float4*)(queries + (size_t)qg * 256 + hl * 8);
  const float4 q1 = *(const float4*)(queries + (size_t)qg * 256 + hl * 8 + 4);
  float a[8];
#pragma unroll
  for (int p = 0; p < 8; ++p) {
    const float4 w0 = *(const float4*)(attn_w + p * 256 + hl * 8);
    const float4 w1 = *(const float4*)(attn_w + p * 256 + hl * 8 + 4);
    float d = q0.x * w0.x + q0.y * w0.y + q0.z * w0.z + q0.w * w0.w
            + q1.x * w1.x + q1.y * w1.y + q1.z * w1.z + q1.w * w1.w;
#pragma unroll
    for (int off = 16; off >= 1; off >>= 1) d += __shfl_xor(d, off);
    a[p] = d + attn_b[p];
  }
  float mx = a[0];
#pragma unroll
  for (int p = 1; p < 8; ++p) mx = fmaxf(mx, a[p]);
  float ssum = 0.f;
#pragma unroll
  for (int p = 0; p < 8; ++p) { a[p] = __expf(a[p] - mx); ssum += a[p]; }
  const float inv = 1.f / ssum;

  float acc[8] = {0.f, 0.f, 0.f, 0.f, 0.f, 0.f, 0.f, 0.f};
  const unsigned short* vb = value + (size_t)b * (128 * 128 * 256);
#pragma unroll
  for (int p = 0; p < 8; ++p) {
    const float ty = traj[(qg * 8 + p) * 2 + 0];
    const float tx = traj[(qg * 8 + p) * 2 + 1];
    const float fx = (tx * 0.03125f + 1.f) * 64.f - 0.5f;   // grid x from traj[...,1]
    const float fy = (ty * 0.03125f + 1.f) * 64.f - 0.5f;   // grid y from traj[...,0]
    const float fx0 = floorf(fx), fy0 = floorf(fy);
    const int ix0 = (int)fx0, iy0 = (int)fy0;
    const float wx1 = fx - fx0, wx0 = 1.f - wx1;
    const float wy1 = fy - fy0, wy0 = 1.f - wy1;
    const float ap = a[p] * inv;
    const float cw[4] = {wx0 * wy0 * ap, wx1 * wy0 * ap, wx0 * wy1 * ap, wx1 * wy1 * ap};
#pragma unroll
    for (int cc = 0; cc < 4; ++cc) {
      const int cx = ix0 + (cc & 1), cy = iy0 + (cc >> 1);
      const bool valid = (cx >= 0) & (cx < 128) & (cy >= 0) & (cy < 128);
      const float w = valid ? cw[cc] : 0.f;
      const int cxc = min(max(cx, 0), 127), cyc = min(max(cy, 0), 127);
      const short8 v = *(const short8*)(vb + (cyc * 128 + cxc) * 256 + hl * 8);
#pragma unroll
      for (int j = 0; j < 8; ++j) acc[j] += w * bf2f((unsigned short)v[j]);
    }
  }
  short8 o;
#pragma unroll
  for (int j = 0; j < 8; ++j) o[j] = (short)f2bf(acc[j]);
  *(short8*)(S + (size_t)qg * 256 + hl * 8) = o;
}

// ---------------------------------------------------------------------------
// K4 v4 (unchanged): barrier-free, S read directly from L2-resident global.
// ---------------------------------------------------------------------------
__global__ __launch_bounds__(256) void k4_proj(const unsigned short* __restrict__ S,
                                               const unsigned short* __restrict__ wout,
                                               const float* __restrict__ out_b,
                                               const float* __restrict__ queries,
                                               float* __restrict__ out) {
  const short8* wp8 = (const short8*)wout;
  const short8* Sp = (const short8*)S;           // [q][32 chunks of 8c]
  const int t = threadIdx.x, wid = t >> 6, lane = t & 63;
  const int q0 = blockIdx.x * 64;
  const int g = lane >> 4, l15 = lane & 15;
  const f32x4 z4 = {0.f, 0.f, 0.f, 0.f};
  f32x4 acc[4][4];
#pragma unroll
  for (int i = 0; i < 4; ++i)
#pragma unroll
    for (int j = 0; j < 4; ++j) acc[i][j] = z4;

#pragma unroll
  for (int ks = 0; ks < 8; ++ks) {
    short8 af[4];
#pragma unroll
    for (int df = 0; df < 4; ++df)
      af[df] = wp8[(ks * 4 + g) * 256 + wid * 64 + df * 16 + l15];
    short8 bf[4];
#pragma unroll
    for (int qf = 0; qf < 4; ++qf)
      bf[qf] = Sp[(size_t)(q0 + qf * 16 + l15) * 32 + ks * 4 + g];
#pragma unroll
    for (int df = 0; df < 4; ++df)
#pragma unroll
      for (int qf = 0; qf < 4; ++qf)
        acc[df][qf] = __builtin_amdgcn_mfma_f32_16x16x32_bf16(af[df], bf[qf], acc[df][qf], 0, 0, 0);
  }

#pragma unroll
  for (int df = 0; df < 4; ++df) {
    const int db = wid * 64 + df * 16 + g * 4;
    const float4 ob4 = *(const float4*)(out_b + db);
#pragma unroll
    for (int qf = 0; qf < 4; ++qf) {
      const int q = q0 + qf * 16 + l15;
      const float4 qv = *(const float4*)(queries + (size_t)q * 256 + db);
      float4 ov;
      ov.x = acc[df][qf][0] + ob4.x + qv.x;
      ov.y = acc[df][qf][1] + ob4.y + qv.y;
      ov.z = acc[df][qf][2] + ob4.z + qv.z;
      ov.w = acc[df][qf][3] + ob4.w + qv.w;
      *(float4*)(out + (size_t)q * 256 + db) = ov;
    }
  }
}

// ---------------------------------------------------------------------------
extern "C" void kernel_launch(void* const* d_in, const int* in_sizes, int n_in,
                              void* d_out, int out_size, void* d_ws, size_t ws_size,
                              hipStream_t stream) {
  const float* queries = (const float*)d_in[0];
  const float* traj    = (const float*)d_in[1];
  const float* bev     = (const float*)d_in[2];
  const float* attn_w  = (const float*)d_in[4];
  const float* attn_b  = (const float*)d_in[5];
  const float* conv_w  = (const float*)d_in[6];
  const float* conv_b  = (const float*)d_in[7];
  const float* out_w   = (const float*)d_in[8];
  const float* out_b   = (const float*)d_in[9];
  float* out = (float*)d_out;

  char* ws = (char*)d_ws;
  unsigned short* bev_nhwc = (unsigned short*)(ws);               //  33,554,432 B
  unsigned short* value    = (unsigned short*)(ws + 33554432);    // 134,217,728 B
  unsigned short* wconv    = (unsigned short*)(ws + 167772160);   //     294,912 B
  unsigned short* wout     = (unsigned short*)(ws + 168067072);   //     131,072 B
  unsigned short* Sbuf     = (unsigned short*)(ws + 168198144);   //   8,388,608 B
  float*          zp       = (float*)(ws + 176586752);            //         256 B

  k1_transpose<<<1024, 256, 0, stream>>>(bev, bev_nhwc, conv_w, out_w, wconv, wout, zp);
  k2_conv<<<2048, 256, 0, stream>>>(bev_nhwc, wconv, conv_b, zp, value);
  k3_sample<<<2048, 256, 0, stream>>>(queries, traj, attn_w, attn_b, value, Sbuf);
  k4_proj<<<256, 256, 0, stream>>>(Sbuf, wout, out_b, queries, out);
}